// Round 1
// baseline (395.679 us; speedup 1.0000x reference)
//
#include <hip/hip_runtime.h>
#include <stdint.h>

typedef float floatx4 __attribute__((ext_vector_type(4)));

#define FP8_MAX 448.0f
#define BM 128
#define BN 128
#define BK 64

// ---------------------------------------------------------------- init
__global__ void init_amax(unsigned* amaxs) {
    if (threadIdx.x < 2) amaxs[threadIdx.x] = 0u;
}

// ---------------------------------------------------------------- amax
__global__ void amax_kernel(const float* __restrict__ p, long n4,
                            unsigned* __restrict__ out) {
    const float4* p4 = (const float4*)p;
    float m = 0.0f;
    long stride = (long)gridDim.x * blockDim.x;
    for (long i = (long)blockIdx.x * blockDim.x + threadIdx.x; i < n4; i += stride) {
        float4 v = p4[i];
        m = fmaxf(m, fmaxf(fmaxf(fabsf(v.x), fabsf(v.y)),
                           fmaxf(fabsf(v.z), fabsf(v.w))));
    }
    // wave-64 reduction
    #pragma unroll
    for (int off = 32; off > 0; off >>= 1)
        m = fmaxf(m, __shfl_down(m, off, 64));
    __shared__ float red[8];
    int wave = threadIdx.x >> 6;
    if ((threadIdx.x & 63) == 0) red[wave] = m;
    __syncthreads();
    if (threadIdx.x == 0) {
        int nw = blockDim.x >> 6;
        float b = red[0];
        for (int i = 1; i < nw; ++i) b = fmaxf(b, red[i]);
        atomicMax(out, __float_as_uint(b));  // all values >= 0: uint order == float order
    }
}

// ---------------------------------------------------------------- quant
// 16 floats -> 16 fp8 bytes per thread per iteration (int4 store).
__global__ void quant_kernel(const float* __restrict__ in, int4* __restrict__ out,
                             long n16, const unsigned* __restrict__ amax_bits) {
    float a = __uint_as_float(*amax_bits);
    float s = FP8_MAX / fmaxf(a, 1e-12f);
    const float4* p4 = (const float4*)in;
    long stride = (long)gridDim.x * blockDim.x;
    for (long i = (long)blockIdx.x * blockDim.x + threadIdx.x; i < n16; i += stride) {
        float4 v0 = p4[i * 4 + 0];
        float4 v1 = p4[i * 4 + 1];
        float4 v2 = p4[i * 4 + 2];
        float4 v3 = p4[i * 4 + 3];
        int w0 = 0, w1 = 0, w2 = 0, w3 = 0;
        w0 = __builtin_amdgcn_cvt_pk_fp8_f32(v0.x * s, v0.y * s, w0, false);
        w0 = __builtin_amdgcn_cvt_pk_fp8_f32(v0.z * s, v0.w * s, w0, true);
        w1 = __builtin_amdgcn_cvt_pk_fp8_f32(v1.x * s, v1.y * s, w1, false);
        w1 = __builtin_amdgcn_cvt_pk_fp8_f32(v1.z * s, v1.w * s, w1, true);
        w2 = __builtin_amdgcn_cvt_pk_fp8_f32(v2.x * s, v2.y * s, w2, false);
        w2 = __builtin_amdgcn_cvt_pk_fp8_f32(v2.z * s, v2.w * s, w2, true);
        w3 = __builtin_amdgcn_cvt_pk_fp8_f32(v3.x * s, v3.y * s, w3, false);
        w3 = __builtin_amdgcn_cvt_pk_fp8_f32(v3.z * s, v3.w * s, w3, true);
        out[i] = make_int4(w0, w1, w2, w3);
    }
}

// ---------------------------------------------------------------- GEMM
// A: [M][K] fp8 (activations), B: [N][K] fp8 (weight, already B^T layout),
// out[m][n] = (sum_k A[m][k]*B[n][k]) * inv_scale + bias[n]
// m97 structure: 128x128 tile, BK=64, 4 waves in 2x2, each 64x64 via 4x4
// grid of 16x16x32 fp8 MFMAs. global_load_lds width-16 staging.
__global__ __launch_bounds__(256) void gemm_fp8(
    const unsigned char* __restrict__ Aq, const unsigned char* __restrict__ Bq,
    const float* __restrict__ bias, const unsigned* __restrict__ amaxs,
    float* __restrict__ out, int M, int N, int K) {
    __shared__ __align__(16) unsigned char tileA[BM * BK];
    __shared__ __align__(16) unsigned char tileB[BN * BK];

    const int tid = threadIdx.x;
    const int lane = tid & 63;
    const int wave = tid >> 6;
    const int waveM = (wave & 1) * 64;
    const int waveN = (wave >> 1) * 64;
    const long m0 = (long)blockIdx.x * BM;
    const int n0 = blockIdx.y * BN;

    // staging coords: per wave-call, 16 rows x 64 bytes, lane L -> chunk L*16
    const int srow = lane >> 2;          // 0..15
    const int scol = (lane & 3) * 16;    // 0,16,32,48

    floatx4 acc[4][4];
    #pragma unroll
    for (int i = 0; i < 4; ++i)
        #pragma unroll
        for (int j = 0; j < 4; ++j)
            acc[i][j] = (floatx4){0.f, 0.f, 0.f, 0.f};

    const int row16 = lane & 15;
    const int quad = lane >> 4;

    for (int k0 = 0; k0 < K; k0 += BK) {
        __syncthreads();  // previous iteration's LDS reads done
        #pragma unroll
        for (int c = 0; c < 2; ++c) {
            const int rbase = (wave * 2 + c) * 16;
            const unsigned char* gA = Aq + (m0 + rbase + srow) * (long)K + k0 + scol;
            const unsigned char* gB = Bq + ((long)(n0 + rbase + srow)) * (long)K + k0 + scol;
            __builtin_amdgcn_global_load_lds(
                (const __attribute__((address_space(1))) void*)gA,
                (__attribute__((address_space(3))) void*)&tileA[(rbase + srow) * BK + scol],
                16, 0, 0);
            __builtin_amdgcn_global_load_lds(
                (const __attribute__((address_space(1))) void*)gB,
                (__attribute__((address_space(3))) void*)&tileB[(rbase + srow) * BK + scol],
                16, 0, 0);
        }
        __syncthreads();  // staging visible (barrier drains vmcnt)

        #pragma unroll
        for (int kc = 0; kc < 2; ++kc) {
            const int kb = kc * 32 + quad * 8;
            long a[4], b[4];
            #pragma unroll
            for (int t = 0; t < 4; ++t)
                a[t] = *(const long*)&tileA[(waveM + t * 16 + row16) * BK + kb];
            #pragma unroll
            for (int t = 0; t < 4; ++t)
                b[t] = *(const long*)&tileB[(waveN + t * 16 + row16) * BK + kb];
            #pragma unroll
            for (int mt = 0; mt < 4; ++mt)
                #pragma unroll
                for (int nt = 0; nt < 4; ++nt)
                    acc[mt][nt] = __builtin_amdgcn_mfma_f32_16x16x32_fp8_fp8(
                        a[mt], b[nt], acc[mt][nt], 0, 0, 0);
        }
    }

    // epilogue: dequant + bias
    const float ax = __uint_as_float(amaxs[0]);
    const float aw = __uint_as_float(amaxs[1]);
    const float sx = FP8_MAX / fmaxf(ax, 1e-12f);
    const float sw = FP8_MAX / fmaxf(aw, 1e-12f);
    const float inv = 1.0f / (sx * sw);

    const int col = lane & 15;          // C/D: col = lane&15
    const int rbase4 = (lane >> 4) * 4; // row = (lane>>4)*4 + reg
    #pragma unroll
    for (int nt = 0; nt < 4; ++nt) {
        const int gn = n0 + waveN + nt * 16 + col;
        const float bv = bias[gn];
        #pragma unroll
        for (int mt = 0; mt < 4; ++mt) {
            const long gm = m0 + waveM + mt * 16 + rbase4;
            float* po = out + gm * (long)N + gn;
            #pragma unroll
            for (int r = 0; r < 4; ++r)
                po[(long)r * N] = acc[mt][nt][r] * inv + bv;
        }
    }
}

// ---------------------------------------------------------------- launch
extern "C" void kernel_launch(void* const* d_in, const int* in_sizes, int n_in,
                              void* d_out, int out_size, void* d_ws, size_t ws_size,
                              hipStream_t stream) {
    const float* x = (const float*)d_in[0];
    const float* w = (const float*)d_in[1];
    const float* bias = (const float*)d_in[2];
    float* out = (float*)d_out;

    const long nx = in_sizes[0];          // M*K
    const long nw = in_sizes[1];          // N*K
    const int N = in_sizes[2];            // 1024
    const long K = nw / N;                // 1024
    const long M = nx / K;                // 32768

    unsigned char* ws = (unsigned char*)d_ws;
    unsigned* amaxs = (unsigned*)ws;                  // [0]=x amax bits, [1]=w amax bits
    unsigned char* xq = ws + 256;                     // M*K fp8
    unsigned char* wq = xq + nx;                      // N*K fp8

    init_amax<<<1, 64, 0, stream>>>(amaxs);
    amax_kernel<<<2048, 256, 0, stream>>>(x, nx / 4, amaxs + 0);
    amax_kernel<<<256, 256, 0, stream>>>(w, nw / 4, amaxs + 1);
    quant_kernel<<<2048, 256, 0, stream>>>(x, (int4*)xq, nx / 16, amaxs + 0);
    quant_kernel<<<256, 256, 0, stream>>>(w, (int4*)wq, nw / 16, amaxs + 1);

    dim3 grid((int)(M / BM), N / BN);
    gemm_fp8<<<grid, 256, 0, stream>>>(xq, wq, bias, amaxs, out,
                                       (int)M, N, (int)K);
}

// Round 2
// 301.719 us; speedup vs baseline: 1.3114x; 1.3114x over previous
//
#include <hip/hip_runtime.h>
#include <stdint.h>

typedef float floatx4 __attribute__((ext_vector_type(4)));
typedef int intx8 __attribute__((ext_vector_type(8)));

#define FP8_MAX 448.0f
#define BM 128
#define BN 128
#define BK 128
#define GX 2048   // blocks covering x in amax/quant
#define GW 256    // blocks covering w

// ---------------------------------------------------------------- amax partials
__global__ void amax_partial(const float* __restrict__ x, long n4x,
                             const float* __restrict__ w, long n4w,
                             float* __restrict__ part) {
    const float4* p4; long n4, i0, stride;
    if (blockIdx.x < GX) {
        p4 = (const float4*)x; n4 = n4x;
        i0 = (long)blockIdx.x * blockDim.x + threadIdx.x;
        stride = (long)GX * blockDim.x;
    } else {
        p4 = (const float4*)w; n4 = n4w;
        i0 = (long)(blockIdx.x - GX) * blockDim.x + threadIdx.x;
        stride = (long)GW * blockDim.x;
    }
    float m = 0.f;
    for (long i = i0; i < n4; i += stride) {
        float4 v = p4[i];
        m = fmaxf(m, fmaxf(fmaxf(fabsf(v.x), fabsf(v.y)),
                           fmaxf(fabsf(v.z), fabsf(v.w))));
    }
    #pragma unroll
    for (int off = 32; off > 0; off >>= 1) m = fmaxf(m, __shfl_down(m, off, 64));
    __shared__ float red[4];
    if ((threadIdx.x & 63) == 0) red[threadIdx.x >> 6] = m;
    __syncthreads();
    if (threadIdx.x == 0)
        part[blockIdx.x] = fmaxf(fmaxf(red[0], red[1]), fmaxf(red[2], red[3]));
}

// ---------------------------------------------------------------- finalize scales
__global__ void finalize_scales(const float* __restrict__ part, float* __restrict__ scales) {
    float mx = 0.f, mw = 0.f;
    for (int i = threadIdx.x; i < GX; i += 256) mx = fmaxf(mx, part[i]);
    for (int i = GX + threadIdx.x; i < GX + GW; i += 256) mw = fmaxf(mw, part[i]);
    #pragma unroll
    for (int off = 32; off > 0; off >>= 1) {
        mx = fmaxf(mx, __shfl_down(mx, off, 64));
        mw = fmaxf(mw, __shfl_down(mw, off, 64));
    }
    __shared__ float rx[4], rw[4];
    if ((threadIdx.x & 63) == 0) { rx[threadIdx.x >> 6] = mx; rw[threadIdx.x >> 6] = mw; }
    __syncthreads();
    if (threadIdx.x == 0) {
        float ax = fmaxf(fmaxf(rx[0], rx[1]), fmaxf(rx[2], rx[3]));
        float aw = fmaxf(fmaxf(rw[0], rw[1]), fmaxf(rw[2], rw[3]));
        float sx = FP8_MAX / fmaxf(ax, 1e-12f);
        float sw = FP8_MAX / fmaxf(aw, 1e-12f);
        scales[0] = sx; scales[1] = sw; scales[2] = 1.0f / (sx * sw);
    }
}

// ---------------------------------------------------------------- fused quant (x and w)
__global__ void quant_kernel(const float* __restrict__ x, int4* __restrict__ xq, long n16x,
                             const float* __restrict__ w, int4* __restrict__ wq, long n16w,
                             const float* __restrict__ scales) {
    const float4* p4; int4* o; long n16, i0, stride; float s;
    if (blockIdx.x < GX) {
        p4 = (const float4*)x; o = xq; n16 = n16x; s = scales[0];
        i0 = (long)blockIdx.x * blockDim.x + threadIdx.x;
        stride = (long)GX * blockDim.x;
    } else {
        p4 = (const float4*)w; o = wq; n16 = n16w; s = scales[1];
        i0 = (long)(blockIdx.x - GX) * blockDim.x + threadIdx.x;
        stride = (long)GW * blockDim.x;
    }
    for (long i = i0; i < n16; i += stride) {
        float4 v0 = p4[i * 4 + 0];
        float4 v1 = p4[i * 4 + 1];
        float4 v2 = p4[i * 4 + 2];
        float4 v3 = p4[i * 4 + 3];
        int w0 = 0, w1 = 0, w2 = 0, w3 = 0;
        w0 = __builtin_amdgcn_cvt_pk_fp8_f32(v0.x * s, v0.y * s, w0, false);
        w0 = __builtin_amdgcn_cvt_pk_fp8_f32(v0.z * s, v0.w * s, w0, true);
        w1 = __builtin_amdgcn_cvt_pk_fp8_f32(v1.x * s, v1.y * s, w1, false);
        w1 = __builtin_amdgcn_cvt_pk_fp8_f32(v1.z * s, v1.w * s, w1, true);
        w2 = __builtin_amdgcn_cvt_pk_fp8_f32(v2.x * s, v2.y * s, w2, false);
        w2 = __builtin_amdgcn_cvt_pk_fp8_f32(v2.z * s, v2.w * s, w2, true);
        w3 = __builtin_amdgcn_cvt_pk_fp8_f32(v3.x * s, v3.y * s, w3, false);
        w3 = __builtin_amdgcn_cvt_pk_fp8_f32(v3.z * s, v3.w * s, w3, true);
        o[i] = make_int4(w0, w1, w2, w3);
    }
}

// ---------------------------------------------------------------- GEMM (MX-scaled fp8, unit scales)
// A: [M][K] fp8, B: [N][K] fp8.  out[m][n] = (sum A*B) * inv + bias[n]
// LDS: row-major 128x128 bytes, 16B chunks XOR-swizzled: phys = log ^ (row&7).
// Staging: global_load_lds 16B, one call = 8 rows x 128B, fully coalesced.
// Fragments: 16x16x128 scaled MFMA; lane holds 32 contiguous k-bytes = 2x b128.
__global__ __launch_bounds__(256) void gemm_fp8mx(
    const unsigned char* __restrict__ Aq, const unsigned char* __restrict__ Bq,
    const float* __restrict__ bias, const float* __restrict__ scales,
    float* __restrict__ out, int M, int N, int K) {
    __shared__ __align__(16) unsigned char tA[BM * BK];
    __shared__ __align__(16) unsigned char tB[BN * BK];

    const int tid = threadIdx.x;
    const int lane = tid & 63;
    const int wave = tid >> 6;
    const int waveM = (wave & 1) * 64;
    const int waveN = (wave >> 1) * 64;
    const long m0 = (long)blockIdx.y * BM;   // grid.y = M/BM
    const int n0 = blockIdx.x * BN;          // grid.x = N/BN (fastest -> A-tile reuse in L2)

    const int srow = lane >> 3;   // 0..7 row within staging call
    const int sphys = lane & 7;   // physical 16B chunk

    floatx4 acc[4][4];
    #pragma unroll
    for (int i = 0; i < 4; ++i)
        #pragma unroll
        for (int j = 0; j < 4; ++j)
            acc[i][j] = (floatx4){0.f, 0.f, 0.f, 0.f};

    const int row16 = lane & 15;
    const int q2 = (lane >> 4) * 2;   // logical chunk base = 2*quad

    for (int k0 = 0; k0 < K; k0 += BK) {
        __syncthreads();
        #pragma unroll
        for (int c = 0; c < 4; ++c) {
            const int r = wave * 32 + c * 8 + srow;
            const int lc = (sphys ^ (r & 7)) * 16;   // logical byte offset in row
            __builtin_amdgcn_global_load_lds(
                (const __attribute__((address_space(1))) void*)(Aq + (m0 + r) * (long)K + k0 + lc),
                (__attribute__((address_space(3))) void*)&tA[r * BK + sphys * 16], 16, 0, 0);
            __builtin_amdgcn_global_load_lds(
                (const __attribute__((address_space(1))) void*)(Bq + (long)(n0 + r) * K + k0 + lc),
                (__attribute__((address_space(3))) void*)&tB[r * BK + sphys * 16], 16, 0, 0);
        }
        __syncthreads();

        intx8 af[4], bf[4];
        #pragma unroll
        for (int t = 0; t < 4; ++t) {
            const int row = waveM + t * 16 + row16;
            const int s = row & 7;
            const int4 lo = *(const int4*)&tA[row * BK + ((q2 ^ s)) * 16];
            const int4 hi = *(const int4*)&tA[row * BK + (((q2 + 1) ^ s)) * 16];
            af[t] = (intx8){lo.x, lo.y, lo.z, lo.w, hi.x, hi.y, hi.z, hi.w};
        }
        #pragma unroll
        for (int t = 0; t < 4; ++t) {
            const int row = waveN + t * 16 + row16;
            const int s = row & 7;
            const int4 lo = *(const int4*)&tB[row * BK + ((q2 ^ s)) * 16];
            const int4 hi = *(const int4*)&tB[row * BK + (((q2 + 1) ^ s)) * 16];
            bf[t] = (intx8){lo.x, lo.y, lo.z, lo.w, hi.x, hi.y, hi.z, hi.w};
        }
        #pragma unroll
        for (int mt = 0; mt < 4; ++mt)
            #pragma unroll
            for (int nt = 0; nt < 4; ++nt)
                acc[mt][nt] = __builtin_amdgcn_mfma_scale_f32_16x16x128_f8f6f4(
                    af[mt], bf[nt], acc[mt][nt], 0, 0, /*A=fp8,B=fp8*/
                    0, 127, 0, 127);                   /* unit E8M0 scales */
    }

    const float inv = scales[2];
    const int col = lane & 15;          // C/D: col = lane&15
    const int rbase4 = (lane >> 4) * 4; // row = quad*4 + reg
    #pragma unroll
    for (int nt = 0; nt < 4; ++nt) {
        const int gn = n0 + waveN + nt * 16 + col;
        const float bv = bias[gn];
        #pragma unroll
        for (int mt = 0; mt < 4; ++mt) {
            const long gm = m0 + waveM + mt * 16 + rbase4;
            float* po = out + gm * (long)N + gn;
            #pragma unroll
            for (int r = 0; r < 4; ++r)
                po[(long)r * N] = acc[mt][nt][r] * inv + bv;
        }
    }
}

// ---------------------------------------------------------------- launch
extern "C" void kernel_launch(void* const* d_in, const int* in_sizes, int n_in,
                              void* d_out, int out_size, void* d_ws, size_t ws_size,
                              hipStream_t stream) {
    const float* x = (const float*)d_in[0];
    const float* w = (const float*)d_in[1];
    const float* bias = (const float*)d_in[2];
    float* out = (float*)d_out;

    const long nx = in_sizes[0];   // M*K
    const long nw = in_sizes[1];   // N*K
    const int N = in_sizes[2];     // 1024
    const long K = nw / N;         // 1024
    const long M = nx / K;         // 32768

    unsigned char* ws = (unsigned char*)d_ws;
    unsigned char* xq = ws;                         // nx bytes fp8
    unsigned char* wq = ws + nx;                    // nw bytes fp8
    float* part = (float*)(ws + nx + nw);           // GX+GW partial maxima
    float* scales = (float*)(ws + nx + nw + 16384); // {sx, sw, inv}

    amax_partial<<<GX + GW, 256, 0, stream>>>(x, nx / 4, w, nw / 4, part);
    finalize_scales<<<1, 256, 0, stream>>>(part, scales);
    quant_kernel<<<GX + GW, 256, 0, stream>>>(x, (int4*)xq, nx / 16,
                                              w, (int4*)wq, nw / 16, scales);

    dim3 grid(N / BN, (int)(M / BM));
    gemm_fp8mx<<<grid, 256, 0, stream>>>(xq, wq, bias, scales, out,
                                         (int)M, N, (int)K);
}